// Round 15
// baseline (75.341 us; speedup 1.0000x reference)
//
#include <hip/hip_runtime.h>

#define LN_EPS 1e-5f

static constexpr int Hc  = 512;
static constexpr int Fc  = 16;
static constexpr int Sc  = 1024;
static constexpr int RPW = 16;       // rows per wave: same s, consecutive b
static constexpr int RD  = 6;        // store ring depth (WAR distance in rows)

// ---- prologue: bsum[h] = sum_i b[i][h] (512 floats into d_ws) ----
__global__ void bsum_kernel(const float* __restrict__ b, float* __restrict__ bsum) {
    int h = blockIdx.x * 64 + threadIdx.x;
    float s = 0.f;
#pragma unroll
    for (int i = 0; i < Fc; ++i) s += b[i * Hc + h];
    bsum[h] = s;
}

// ---- DPP wave64 sum: 6 VALU steps + readlane, no LDS, no barriers ----
template <int CTRL, int RMASK>
__device__ __forceinline__ float dpp_add(float v) {
    int t = __builtin_amdgcn_update_dpp(0, __float_as_int(v), CTRL, RMASK, 0xf, true);
    return v + __int_as_float(t);
}
__device__ __forceinline__ float wave_sum64(float v) {
    v = dpp_add<0x111, 0xf>(v);   // row_shr:1
    v = dpp_add<0x112, 0xf>(v);   // row_shr:2
    v = dpp_add<0x114, 0xf>(v);   // row_shr:4
    v = dpp_add<0x118, 0xf>(v);   // row_shr:8
    v = dpp_add<0x142, 0xa>(v);   // row_bcast:15
    v = dpp_add<0x143, 0xc>(v);   // row_bcast:31 -> lane63 has total
    return __int_as_float(__builtin_amdgcn_readlane(__float_as_int(v), 63));
}
__device__ __forceinline__ float rdlane(float v, int l) {
    return __int_as_float(__builtin_amdgcn_readlane(__float_as_int(v), l));
}

// ---- fused: one wave per (g,s); rows b = g*16..g*16+15 ----
// R15 = R9 (f32 W panel, zero VMEM loads in t-loop, no inter-wave coupling)
// + DEPTH-6 STORE RING: each row's result goes to ring slot t%6, so the
// rewrite of a store's data VGPRs happens 6 rows (~2700 issue-cyc) after the
// store issued, and up to 12 stores/wave stay in flight. Rationale: stores
// hold data VGPRs until vmcnt retires them; depth-1/2 recycling (R6..R14)
// forces a wait on store COMPLETION every row -- the one mechanism consistent
// with compute-restructures all being neutral while memset (constant data
// reg = infinite depth) streams 7 TB/s at the same occupancy.
// No launch_bounds min-waves (R4/R11: it caps VGPR below need and spills).
__global__ __launch_bounds__(256) void fused_kernel(
    const float* __restrict__ x, const float* __restrict__ W,
    const float* __restrict__ emb, const float* __restrict__ bsum,
    const float* __restrict__ gamma, const float* __restrict__ beta,
    float* __restrict__ out)
{
    const int lane = threadIdx.x & 63;
    const int wid  = (blockIdx.x << 2) | (threadIdx.x >> 6);   // 0..8191
    const int s    = wid & (Sc - 1);
    const int g    = wid >> 10;                                // 0..7
    const int h0 = lane * 4, h1 = h0 + 256;

    // register-resident W panel: 16 K-rows x 8 cols per lane (128 VGPR)
    float4 w0[Fc], w1[Fc];
#pragma unroll
    for (int i = 0; i < Fc; ++i) {
        w0[i] = *reinterpret_cast<const float4*>(&W[i * Hc + h0]);
        w1[i] = *reinterpret_cast<const float4*>(&W[i * Hc + h1]);
    }

    // x for all 16 rows up front: 4 gather loads (4 x 64B segments each)
    const int sub = lane >> 4, i16 = lane & 15;
    float xq0, xq1, xq2, xq3;
    {
        const size_t xoff = (size_t)s * Fc + i16;
        xq0 = __builtin_nontemporal_load(&x[(size_t)(g * 16 +  0 + sub) * Sc * Fc + xoff]);
        xq1 = __builtin_nontemporal_load(&x[(size_t)(g * 16 +  4 + sub) * Sc * Fc + xoff]);
        xq2 = __builtin_nontemporal_load(&x[(size_t)(g * 16 +  8 + sub) * Sc * Fc + xoff]);
        xq3 = __builtin_nontemporal_load(&x[(size_t)(g * 16 + 12 + sub) * Sc * Fc + xoff]);
    }

    // loop-invariant per-wave vectors
    const float4 g0  = *reinterpret_cast<const float4*>(&gamma[h0]);
    const float4 g1  = *reinterpret_cast<const float4*>(&gamma[h1]);
    const float4 be0 = *reinterpret_cast<const float4*>(&beta[h0]);
    const float4 be1 = *reinterpret_cast<const float4*>(&beta[h1]);
    float4 ebs0, ebs1;
    {
        const float4 e0  = *reinterpret_cast<const float4*>(&emb[(size_t)s * Hc + h0]);
        const float4 e1  = *reinterpret_cast<const float4*>(&emb[(size_t)s * Hc + h1]);
        const float4 bs0 = *reinterpret_cast<const float4*>(&bsum[h0]);
        const float4 bs1 = *reinterpret_cast<const float4*>(&bsum[h1]);
        ebs0.x = e0.x + bs0.x; ebs0.y = e0.y + bs0.y; ebs0.z = e0.z + bs0.z; ebs0.w = e0.w + bs0.w;
        ebs1.x = e1.x + bs1.x; ebs1.y = e1.y + bs1.y; ebs1.z = e1.z + bs1.z; ebs1.w = e1.w + bs1.w;
    }

    // store ring: distinct VGPR sets for RD consecutive rows (static indices)
    float4 r0[RD], r1[RD];

#pragma unroll
    for (int t = 0; t < RPW; ++t) {
        const int slot = t % RD;   // compile-time after full unroll
        const float xsrc = (t >> 2) == 0 ? xq0 : (t >> 2) == 1 ? xq1 : (t >> 2) == 2 ? xq2 : xq3;

        // pure-register FMA chain
        float4 a0 = ebs0, a1 = ebs1;
#pragma unroll
        for (int i = 0; i < Fc; ++i) {
            const float xi = rdlane(xsrc, (t & 3) * 16 + i);
            a0.x = fmaf(xi, w0[i].x, a0.x);
            a0.y = fmaf(xi, w0[i].y, a0.y);
            a0.z = fmaf(xi, w0[i].z, a0.z);
            a0.w = fmaf(xi, w0[i].w, a0.w);
            a1.x = fmaf(xi, w1[i].x, a1.x);
            a1.y = fmaf(xi, w1[i].y, a1.y);
            a1.z = fmaf(xi, w1[i].z, a1.z);
            a1.w = fmaf(xi, w1[i].w, a1.w);
        }

        float psum = a0.x + a0.y + a0.z + a0.w + a1.x + a1.y + a1.z + a1.w;
        float pssq = fmaf(a0.x, a0.x, fmaf(a0.y, a0.y, fmaf(a0.z, a0.z, a0.w * a0.w)));
        pssq = fmaf(a1.x, a1.x, fmaf(a1.y, a1.y, fmaf(a1.z, a1.z, fmaf(a1.w, a1.w, pssq))));

        const float sum = wave_sum64(psum);
        const float ssq = wave_sum64(pssq);

        const float mean = sum * (1.0f / 512.0f);
        const float var  = ssq * (1.0f / 512.0f) - mean * mean;
        const float rs   = rsqrtf(var + LN_EPS);
        const float nmrs = -mean * rs;   // (a-mean)*rs == fma(a, rs, nmrs)

        r0[slot].x = fmaf(fmaf(a0.x, rs, nmrs), g0.x, be0.x);
        r0[slot].y = fmaf(fmaf(a0.y, rs, nmrs), g0.y, be0.y);
        r0[slot].z = fmaf(fmaf(a0.z, rs, nmrs), g0.z, be0.z);
        r0[slot].w = fmaf(fmaf(a0.w, rs, nmrs), g0.w, be0.w);
        r1[slot].x = fmaf(fmaf(a1.x, rs, nmrs), g1.x, be1.x);
        r1[slot].y = fmaf(fmaf(a1.y, rs, nmrs), g1.y, be1.y);
        r1[slot].z = fmaf(fmaf(a1.z, rs, nmrs), g1.z, be1.z);
        r1[slot].w = fmaf(fmaf(a1.w, rs, nmrs), g1.w, be1.w);

        float* orow = out + ((size_t)(g * 16 + t) * Sc + s) * Hc;
        *reinterpret_cast<float4*>(&orow[h0]) = r0[slot];
        *reinterpret_cast<float4*>(&orow[h1]) = r1[slot];
    }
}

extern "C" void kernel_launch(void* const* d_in, const int* in_sizes, int n_in,
                              void* d_out, int out_size, void* d_ws, size_t ws_size,
                              hipStream_t stream) {
    const float* x     = (const float*)d_in[0];
    const float* W     = (const float*)d_in[1];
    const float* b     = (const float*)d_in[2];
    const float* emb   = (const float*)d_in[3];
    const float* gamma = (const float*)d_in[4];
    const float* beta  = (const float*)d_in[5];
    float* out  = (float*)d_out;
    float* bsum = (float*)d_ws;     // 512 floats

    bsum_kernel<<<Hc / 64, 64, 0, stream>>>(b, bsum);

    const int blocks = (8 * Sc) / 4;   // 8192 waves, 4 per block
    fused_kernel<<<blocks, 256, 0, stream>>>(x, W, emb, bsum, gamma, beta, out);
}

// Round 16
// 70.681 us; speedup vs baseline: 1.0659x; 1.0659x over previous
//
#include <hip/hip_runtime.h>

#define LN_EPS 1e-5f

static constexpr int Hc  = 512;
static constexpr int Fc  = 16;
static constexpr int Sc  = 1024;

// ---- prologue: bsum[h] = sum_i b[i][h] (512 floats into d_ws) ----
__global__ void bsum_kernel(const float* __restrict__ b, float* __restrict__ bsum) {
    int h = blockIdx.x * 64 + threadIdx.x;
    float s = 0.f;
#pragma unroll
    for (int i = 0; i < Fc; ++i) s += b[i * Hc + h];
    bsum[h] = s;
}

// ---- DPP wave64 sum: 6 VALU steps + readlane, no LDS, no barriers ----
template <int CTRL, int RMASK>
__device__ __forceinline__ float dpp_add(float v) {
    int t = __builtin_amdgcn_update_dpp(0, __float_as_int(v), CTRL, RMASK, 0xf, true);
    return v + __int_as_float(t);
}
__device__ __forceinline__ float wave_sum64(float v) {
    v = dpp_add<0x111, 0xf>(v);   // row_shr:1
    v = dpp_add<0x112, 0xf>(v);   // row_shr:2
    v = dpp_add<0x114, 0xf>(v);   // row_shr:4
    v = dpp_add<0x118, 0xf>(v);   // row_shr:8
    v = dpp_add<0x142, 0xa>(v);   // row_bcast:15
    v = dpp_add<0x143, 0xc>(v);   // row_bcast:31 -> lane63 has total
    return __int_as_float(__builtin_amdgcn_readlane(__float_as_int(v), 63));
}
__device__ __forceinline__ float rdlane(float v, int l) {
    return __int_as_float(__builtin_amdgcn_readlane(__float_as_int(v), l));
}

// bf16 RNE round; pack two cols per u32.
__device__ __forceinline__ unsigned rne16(float f) {
    unsigned u = __float_as_uint(f);
    return (u + 0x7fffu + ((u >> 16) & 1u)) >> 16;
}
__device__ __forceinline__ unsigned pack2(float lo, float hi) {
    return rne16(lo) | (rne16(hi) << 16);
}
__device__ __forceinline__ float lo_f(unsigned p) { return __uint_as_float(p << 16); }
__device__ __forceinline__ float hi_f(unsigned p) { return __uint_as_float(p); }

// ---- fused: one wave per (g,s); rows b = g*16..g*16+15, fixed s ----
// R16 = R12 data structure (bf16-packed W panel 64 VGPR, zero VMEM loads in
// the row loop, no inter-wave coupling) with the CODE FOOTPRINT cut 4x:
// a real q-loop (unroll 1) over 4-row unrolled chunks (~8 KB body) instead of
// a fully-unrolled 16-row body (~30 KB ~ I$ size). Theory: every plateau
// kernel (R6..R15, 66-77us) shared the giant unrolled body; co-resident waves
// at different PCs thrash the per-CU I-cache, adding a fixed fetch stall per
// row that no data-side change touches. xq runtime indexing is avoided with a
// shift-register rotation (3 v_mov per q-iter).
// LB(256,2): VGPR cap 128 (empirical: cap = 256/min_waves) -> 4 waves/SIMD;
// packed-W body needs ~114 so no spill (R14 precedent).
__global__ __launch_bounds__(256, 2) void fused_kernel(
    const float* __restrict__ x, const float* __restrict__ W,
    const float* __restrict__ emb, const float* __restrict__ bsum,
    const float* __restrict__ gamma, const float* __restrict__ beta,
    float* __restrict__ out)
{
    const int lane = threadIdx.x & 63;
    const int wid  = (blockIdx.x << 2) | (threadIdx.x >> 6);   // 0..8191
    const int s    = wid & (Sc - 1);
    const int g    = wid >> 10;                                // 0..7
    const int h0 = lane * 4, h1 = h0 + 256;

    // packed W panel: 16 K-rows x 8 cols per lane in 64 u32
    unsigned p00[Fc], p01[Fc], p10[Fc], p11[Fc];
#pragma unroll
    for (int i = 0; i < Fc; ++i) {
        const float4 wa = *reinterpret_cast<const float4*>(&W[i * Hc + h0]);
        const float4 wb = *reinterpret_cast<const float4*>(&W[i * Hc + h1]);
        p00[i] = pack2(wa.x, wa.y);
        p01[i] = pack2(wa.z, wa.w);
        p10[i] = pack2(wb.x, wb.y);
        p11[i] = pack2(wb.z, wb.w);
    }

    // x for all 16 rows up front: 4 gather loads (4 x 64B segments each)
    const int sub = lane >> 4, i16 = lane & 15;
    float xq0, xq1, xq2, xq3;
    {
        const size_t xoff = (size_t)s * Fc + i16;
        xq0 = __builtin_nontemporal_load(&x[(size_t)(g * 16 +  0 + sub) * Sc * Fc + xoff]);
        xq1 = __builtin_nontemporal_load(&x[(size_t)(g * 16 +  4 + sub) * Sc * Fc + xoff]);
        xq2 = __builtin_nontemporal_load(&x[(size_t)(g * 16 +  8 + sub) * Sc * Fc + xoff]);
        xq3 = __builtin_nontemporal_load(&x[(size_t)(g * 16 + 12 + sub) * Sc * Fc + xoff]);
    }

    // loop-invariant per-wave vectors
    const float4 g0  = *reinterpret_cast<const float4*>(&gamma[h0]);
    const float4 g1  = *reinterpret_cast<const float4*>(&gamma[h1]);
    const float4 be0 = *reinterpret_cast<const float4*>(&beta[h0]);
    const float4 be1 = *reinterpret_cast<const float4*>(&beta[h1]);
    float4 ebs0, ebs1;
    {
        const float4 e0  = *reinterpret_cast<const float4*>(&emb[(size_t)s * Hc + h0]);
        const float4 e1  = *reinterpret_cast<const float4*>(&emb[(size_t)s * Hc + h1]);
        const float4 bs0 = *reinterpret_cast<const float4*>(&bsum[h0]);
        const float4 bs1 = *reinterpret_cast<const float4*>(&bsum[h1]);
        ebs0.x = e0.x + bs0.x; ebs0.y = e0.y + bs0.y; ebs0.z = e0.z + bs0.z; ebs0.w = e0.w + bs0.w;
        ebs1.x = e1.x + bs1.x; ebs1.y = e1.y + bs1.y; ebs1.z = e1.z + bs1.z; ebs1.w = e1.w + bs1.w;
    }

    float* orow = out + ((size_t)(g * 16) * Sc + s) * Hc;

#pragma unroll 1
    for (int q = 0; q < 4; ++q) {
#pragma unroll
        for (int u = 0; u < 4; ++u) {
            // pure-register FMA chain; W unpacked on the fly
            float4 a0 = ebs0, a1 = ebs1;
#pragma unroll
            for (int i = 0; i < Fc; ++i) {
                const float xi = rdlane(xq0, u * 16 + i);   // compile-time lane
                a0.x = fmaf(xi, lo_f(p00[i]), a0.x);
                a0.y = fmaf(xi, hi_f(p00[i]), a0.y);
                a0.z = fmaf(xi, lo_f(p01[i]), a0.z);
                a0.w = fmaf(xi, hi_f(p01[i]), a0.w);
                a1.x = fmaf(xi, lo_f(p10[i]), a1.x);
                a1.y = fmaf(xi, hi_f(p10[i]), a1.y);
                a1.z = fmaf(xi, lo_f(p11[i]), a1.z);
                a1.w = fmaf(xi, hi_f(p11[i]), a1.w);
            }

            float psum = a0.x + a0.y + a0.z + a0.w + a1.x + a1.y + a1.z + a1.w;
            float pssq = fmaf(a0.x, a0.x, fmaf(a0.y, a0.y, fmaf(a0.z, a0.z, a0.w * a0.w)));
            pssq = fmaf(a1.x, a1.x, fmaf(a1.y, a1.y, fmaf(a1.z, a1.z, fmaf(a1.w, a1.w, pssq))));

            const float sum = wave_sum64(psum);
            const float ssq = wave_sum64(pssq);

            const float mean = sum * (1.0f / 512.0f);
            const float var  = ssq * (1.0f / 512.0f) - mean * mean;
            const float rs   = rsqrtf(var + LN_EPS);
            const float nmrs = -mean * rs;

            float4 r0, r1;
            r0.x = fmaf(fmaf(a0.x, rs, nmrs), g0.x, be0.x);
            r0.y = fmaf(fmaf(a0.y, rs, nmrs), g0.y, be0.y);
            r0.z = fmaf(fmaf(a0.z, rs, nmrs), g0.z, be0.z);
            r0.w = fmaf(fmaf(a0.w, rs, nmrs), g0.w, be0.w);
            r1.x = fmaf(fmaf(a1.x, rs, nmrs), g1.x, be1.x);
            r1.y = fmaf(fmaf(a1.y, rs, nmrs), g1.y, be1.y);
            r1.z = fmaf(fmaf(a1.z, rs, nmrs), g1.z, be1.z);
            r1.w = fmaf(fmaf(a1.w, rs, nmrs), g1.w, be1.w);

            *reinterpret_cast<float4*>(&orow[h0]) = r0;
            *reinterpret_cast<float4*>(&orow[h1]) = r1;
            orow += (size_t)Sc * Hc;            // next b-row
        }
        // shift-register rotation: next q consumes xq0
        xq0 = xq1; xq1 = xq2; xq2 = xq3;
    }
}

extern "C" void kernel_launch(void* const* d_in, const int* in_sizes, int n_in,
                              void* d_out, int out_size, void* d_ws, size_t ws_size,
                              hipStream_t stream) {
    const float* x     = (const float*)d_in[0];
    const float* W     = (const float*)d_in[1];
    const float* b     = (const float*)d_in[2];
    const float* emb   = (const float*)d_in[3];
    const float* gamma = (const float*)d_in[4];
    const float* beta  = (const float*)d_in[5];
    float* out  = (float*)d_out;
    float* bsum = (float*)d_ws;     // 512 floats

    bsum_kernel<<<Hc / 64, 64, 0, stream>>>(b, bsum);

    const int blocks = (8 * Sc) / 4;   // 8192 waves, 4 per block
    fused_kernel<<<blocks, 256, 0, stream>>>(x, W, emb, bsum, gamma, beta, out);
}

// Round 17
// 62.755 us; speedup vs baseline: 1.2006x; 1.1263x over previous
//
#include <hip/hip_runtime.h>

#define LN_EPS 1e-5f

static constexpr int Hc  = 512;
static constexpr int Fc  = 16;
static constexpr int Sc  = 1024;
static constexpr int NW  = 4096;     // total waves; row stride for grid-stride
static constexpr int RPW = 32;       // rows per wave (131072 / 4096)

// ---- prologue: bsum[h] = sum_i b[i][h] (512 floats into d_ws) ----
__global__ void bsum_kernel(const float* __restrict__ b, float* __restrict__ bsum) {
    int h = blockIdx.x * 64 + threadIdx.x;
    float s = 0.f;
#pragma unroll
    for (int i = 0; i < Fc; ++i) s += b[i * Hc + h];
    bsum[h] = s;
}

// ---- DPP wave64 sum: 6 VALU steps + readlane, no LDS, no barriers ----
template <int CTRL, int RMASK>
__device__ __forceinline__ float dpp_add(float v) {
    int t = __builtin_amdgcn_update_dpp(0, __float_as_int(v), CTRL, RMASK, 0xf, true);
    return v + __int_as_float(t);
}
__device__ __forceinline__ float wave_sum64(float v) {
    v = dpp_add<0x111, 0xf>(v);   // row_shr:1
    v = dpp_add<0x112, 0xf>(v);   // row_shr:2
    v = dpp_add<0x114, 0xf>(v);   // row_shr:4
    v = dpp_add<0x118, 0xf>(v);   // row_shr:8
    v = dpp_add<0x142, 0xa>(v);   // row_bcast:15
    v = dpp_add<0x143, 0xc>(v);   // row_bcast:31 -> lane63 has total
    return __int_as_float(__builtin_amdgcn_readlane(__float_as_int(v), 63));
}
__device__ __forceinline__ float rdlane(float v, int l) {
    return __int_as_float(__builtin_amdgcn_readlane(__float_as_int(v), l));
}

// bf16 RNE round; pack two cols per u32.
__device__ __forceinline__ unsigned rne16(float f) {
    unsigned u = __float_as_uint(f);
    return (u + 0x7fffu + ((u >> 16) & 1u)) >> 16;
}
__device__ __forceinline__ unsigned pack2(float lo, float hi) {
    return rne16(lo) | (rne16(hi) << 16);
}
__device__ __forceinline__ float lo_f(unsigned p) { return __uint_as_float(p << 16); }
__device__ __forceinline__ float hi_f(unsigned p) { return __uint_as_float(p); }

// ---- fused: wave w handles rows r = w + k*NW (k=0..31) ----
// DENSE WRITE BAND: at step k all 4096 waves write CONSECUTIVE rows
// [k*4096, (k+1)*4096) -- an 8 MB window marching through out, mimicking
// memset's address->time ordering (memset: 7 TB/s; our scattered-tile
// versions: 4.4 TB/s drain-bound -- the one structural difference left).
// Since NW % Sc == 0: s = r & 1023 = w & 1023 is LOOP-INVARIANT -> emb/ebs
// still hoisted; all 8 x-gathers (32 rows) prefetched up front.
// W bf16-packed (64 VGPR); natural allocation (~115), no min-waves cap
// (R4/R11: cap below need spills catastrophically).
__global__ __launch_bounds__(256) void fused_kernel(
    const float* __restrict__ x, const float* __restrict__ W,
    const float* __restrict__ emb, const float* __restrict__ bsum,
    const float* __restrict__ gamma, const float* __restrict__ beta,
    float* __restrict__ out)
{
    const int lane = threadIdx.x & 63;
    const int w    = (blockIdx.x << 2) | (threadIdx.x >> 6);   // 0..4095
    const int s    = w & (Sc - 1);
    const int h0 = lane * 4, h1 = h0 + 256;

    // packed W panel: 16 K-rows x 8 cols per lane in 64 u32
    unsigned p00[Fc], p01[Fc], p10[Fc], p11[Fc];
#pragma unroll
    for (int i = 0; i < Fc; ++i) {
        const float4 wa = *reinterpret_cast<const float4*>(&W[i * Hc + h0]);
        const float4 wb = *reinterpret_cast<const float4*>(&W[i * Hc + h1]);
        p00[i] = pack2(wa.x, wa.y);
        p01[i] = pack2(wa.z, wa.w);
        p10[i] = pack2(wb.x, wb.y);
        p11[i] = pack2(wb.z, wb.w);
    }

    // x for all 32 rows up front: 8 gather loads; xq[q] lane l holds
    // x[r = (q*4 + (l>>4))*NW + w][l&15]  (4 x 64B segments per instr)
    const int sub = lane >> 4, i16 = lane & 15;
    float xq[8];
#pragma unroll
    for (int q = 0; q < 8; ++q)
        xq[q] = __builtin_nontemporal_load(
            &x[((size_t)(q * 4 + sub) * NW + w) * Fc + i16]);

    // loop-invariant per-wave vectors
    const float4 g0  = *reinterpret_cast<const float4*>(&gamma[h0]);
    const float4 g1  = *reinterpret_cast<const float4*>(&gamma[h1]);
    const float4 be0 = *reinterpret_cast<const float4*>(&beta[h0]);
    const float4 be1 = *reinterpret_cast<const float4*>(&beta[h1]);
    float4 ebs0, ebs1;
    {
        const float4 e0  = *reinterpret_cast<const float4*>(&emb[(size_t)s * Hc + h0]);
        const float4 e1  = *reinterpret_cast<const float4*>(&emb[(size_t)s * Hc + h1]);
        const float4 bs0 = *reinterpret_cast<const float4*>(&bsum[h0]);
        const float4 bs1 = *reinterpret_cast<const float4*>(&bsum[h1]);
        ebs0.x = e0.x + bs0.x; ebs0.y = e0.y + bs0.y; ebs0.z = e0.z + bs0.z; ebs0.w = e0.w + bs0.w;
        ebs1.x = e1.x + bs1.x; ebs1.y = e1.y + bs1.y; ebs1.z = e1.z + bs1.z; ebs1.w = e1.w + bs1.w;
    }

#pragma unroll 1
    for (int q = 0; q < 8; ++q) {
#pragma unroll
        for (int u = 0; u < 4; ++u) {
            // pure-register FMA chain; W unpacked on the fly
            float4 a0 = ebs0, a1 = ebs1;
#pragma unroll
            for (int i = 0; i < Fc; ++i) {
                const float xi = rdlane(xq[0], u * 16 + i);   // compile-time lane
                a0.x = fmaf(xi, lo_f(p00[i]), a0.x);
                a0.y = fmaf(xi, hi_f(p00[i]), a0.y);
                a0.z = fmaf(xi, lo_f(p01[i]), a0.z);
                a0.w = fmaf(xi, hi_f(p01[i]), a0.w);
                a1.x = fmaf(xi, lo_f(p10[i]), a1.x);
                a1.y = fmaf(xi, hi_f(p10[i]), a1.y);
                a1.z = fmaf(xi, lo_f(p11[i]), a1.z);
                a1.w = fmaf(xi, hi_f(p11[i]), a1.w);
            }

            float psum = a0.x + a0.y + a0.z + a0.w + a1.x + a1.y + a1.z + a1.w;
            float pssq = fmaf(a0.x, a0.x, fmaf(a0.y, a0.y, fmaf(a0.z, a0.z, a0.w * a0.w)));
            pssq = fmaf(a1.x, a1.x, fmaf(a1.y, a1.y, fmaf(a1.z, a1.z, fmaf(a1.w, a1.w, pssq))));

            const float sum = wave_sum64(psum);
            const float ssq = wave_sum64(pssq);

            const float mean = sum * (1.0f / 512.0f);
            const float var  = ssq * (1.0f / 512.0f) - mean * mean;
            const float rs   = rsqrtf(var + LN_EPS);
            const float nmrs = -mean * rs;

            float4 r0, r1;
            r0.x = fmaf(fmaf(a0.x, rs, nmrs), g0.x, be0.x);
            r0.y = fmaf(fmaf(a0.y, rs, nmrs), g0.y, be0.y);
            r0.z = fmaf(fmaf(a0.z, rs, nmrs), g0.z, be0.z);
            r0.w = fmaf(fmaf(a0.w, rs, nmrs), g0.w, be0.w);
            r1.x = fmaf(fmaf(a1.x, rs, nmrs), g1.x, be1.x);
            r1.y = fmaf(fmaf(a1.y, rs, nmrs), g1.y, be1.y);
            r1.z = fmaf(fmaf(a1.z, rs, nmrs), g1.z, be1.z);
            r1.w = fmaf(fmaf(a1.w, rs, nmrs), g1.w, be1.w);

            // row r = (q*4+u)*NW + w  -> dense band across waves at fixed k
            float* orow = out + ((size_t)(q * 4 + u) * NW + w) * Hc;
            *reinterpret_cast<float4*>(&orow[h0]) = r0;
            *reinterpret_cast<float4*>(&orow[h1]) = r1;
        }
        // shift-register rotation: next q consumes xq[0]
#pragma unroll
        for (int j = 0; j < 7; ++j) xq[j] = xq[j + 1];
    }
}

extern "C" void kernel_launch(void* const* d_in, const int* in_sizes, int n_in,
                              void* d_out, int out_size, void* d_ws, size_t ws_size,
                              hipStream_t stream) {
    const float* x     = (const float*)d_in[0];
    const float* W     = (const float*)d_in[1];
    const float* b     = (const float*)d_in[2];
    const float* emb   = (const float*)d_in[3];
    const float* gamma = (const float*)d_in[4];
    const float* beta  = (const float*)d_in[5];
    float* out  = (float*)d_out;
    float* bsum = (float*)d_ws;     // 512 floats

    bsum_kernel<<<Hc / 64, 64, 0, stream>>>(b, bsum);

    const int blocks = NW / 4;   // 1024 blocks x 4 waves
    fused_kernel<<<blocks, 256, 0, stream>>>(x, W, emb, bsum, gamma, beta, out);
}

// Round 18
// 61.502 us; speedup vs baseline: 1.2250x; 1.0204x over previous
//
#include <hip/hip_runtime.h>

#define LN_EPS 1e-5f

static constexpr int Hc  = 512;
static constexpr int Fc  = 16;
static constexpr int Sc  = 1024;
static constexpr int NW  = 4096;     // total waves; row stride for grid-stride

// ---- prologue: bsum[h] = sum_i b[i][h] (512 floats into d_ws) ----
__global__ void bsum_kernel(const float* __restrict__ b, float* __restrict__ bsum) {
    int h = blockIdx.x * 64 + threadIdx.x;
    float s = 0.f;
#pragma unroll
    for (int i = 0; i < Fc; ++i) s += b[i * Hc + h];
    bsum[h] = s;
}

// ---- DPP wave64 sum: 6 VALU steps + readlane, no LDS, no barriers ----
template <int CTRL, int RMASK>
__device__ __forceinline__ float dpp_add(float v) {
    int t = __builtin_amdgcn_update_dpp(0, __float_as_int(v), CTRL, RMASK, 0xf, true);
    return v + __int_as_float(t);
}
__device__ __forceinline__ float wave_sum64(float v) {
    v = dpp_add<0x111, 0xf>(v);   // row_shr:1
    v = dpp_add<0x112, 0xf>(v);   // row_shr:2
    v = dpp_add<0x114, 0xf>(v);   // row_shr:4
    v = dpp_add<0x118, 0xf>(v);   // row_shr:8
    v = dpp_add<0x142, 0xa>(v);   // row_bcast:15
    v = dpp_add<0x143, 0xc>(v);   // row_bcast:31 -> lane63 has total
    return __int_as_float(__builtin_amdgcn_readlane(__float_as_int(v), 63));
}
__device__ __forceinline__ float rdlane(float v, int l) {
    return __int_as_float(__builtin_amdgcn_readlane(__float_as_int(v), l));
}

// bf16 RNE round; pack two cols per u32.
__device__ __forceinline__ unsigned rne16(float f) {
    unsigned u = __float_as_uint(f);
    return (u + 0x7fffu + ((u >> 16) & 1u)) >> 16;
}
__device__ __forceinline__ unsigned pack2(float lo, float hi) {
    return rne16(lo) | (rne16(hi) << 16);
}
__device__ __forceinline__ float lo_f(unsigned p) { return __uint_as_float(p << 16); }
__device__ __forceinline__ float hi_f(unsigned p) { return __uint_as_float(p); }

// ---- fused: wave w handles rows r = w + k*NW; dense write band (R17) ----
// R18 = R17 + BURST STORES: each q-batch computes 4 rows into DISTINCT result
// regs (LN done in place), then issues the 8 stores BACK-TO-BACK. The vmcnt
// wait moves off the per-row path (amortized 1/4 rows) and the store stream
// is dense in time, mimicking memset's back-to-back train (7 TB/s) instead of
// compute-store-wait per row (R17: 4.3 TB/s effective).
// LB(256,2): cap 128 VGPR -> 4 waves/SIMD. Budget: W 64 + results 32 + xq 8
// + invariants 24 ~ 128; x readlanes land in SGPRs (no VGPR cost in FMA).
__global__ __launch_bounds__(256, 2) void fused_kernel(
    const float* __restrict__ x, const float* __restrict__ W,
    const float* __restrict__ emb, const float* __restrict__ bsum,
    const float* __restrict__ gamma, const float* __restrict__ beta,
    float* __restrict__ out)
{
    const int lane = threadIdx.x & 63;
    const int w    = (blockIdx.x << 2) | (threadIdx.x >> 6);   // 0..4095
    const int s    = w & (Sc - 1);
    const int h0 = lane * 4, h1 = h0 + 256;

    // packed W panel: 16 K-rows x 8 cols per lane in 64 u32
    unsigned p00[Fc], p01[Fc], p10[Fc], p11[Fc];
#pragma unroll
    for (int i = 0; i < Fc; ++i) {
        const float4 wa = *reinterpret_cast<const float4*>(&W[i * Hc + h0]);
        const float4 wb = *reinterpret_cast<const float4*>(&W[i * Hc + h1]);
        p00[i] = pack2(wa.x, wa.y);
        p01[i] = pack2(wa.z, wa.w);
        p10[i] = pack2(wb.x, wb.y);
        p11[i] = pack2(wb.z, wb.w);
    }

    // x for all 32 rows up front: 8 gather loads; xq[q] lane l holds
    // x[r = (q*4 + (l>>4))*NW + w][l&15]
    const int sub = lane >> 4, i16 = lane & 15;
    float xq[8];
#pragma unroll
    for (int q = 0; q < 8; ++q)
        xq[q] = __builtin_nontemporal_load(
            &x[((size_t)(q * 4 + sub) * NW + w) * Fc + i16]);

    // loop-invariant per-wave vectors
    const float4 g0  = *reinterpret_cast<const float4*>(&gamma[h0]);
    const float4 g1  = *reinterpret_cast<const float4*>(&gamma[h1]);
    const float4 be0 = *reinterpret_cast<const float4*>(&beta[h0]);
    const float4 be1 = *reinterpret_cast<const float4*>(&beta[h1]);
    float4 ebs0, ebs1;
    {
        const float4 e0  = *reinterpret_cast<const float4*>(&emb[(size_t)s * Hc + h0]);
        const float4 e1  = *reinterpret_cast<const float4*>(&emb[(size_t)s * Hc + h1]);
        const float4 bs0 = *reinterpret_cast<const float4*>(&bsum[h0]);
        const float4 bs1 = *reinterpret_cast<const float4*>(&bsum[h1]);
        ebs0.x = e0.x + bs0.x; ebs0.y = e0.y + bs0.y; ebs0.z = e0.z + bs0.z; ebs0.w = e0.w + bs0.w;
        ebs1.x = e1.x + bs1.x; ebs1.y = e1.y + bs1.y; ebs1.z = e1.z + bs1.z; ebs1.w = e1.w + bs1.w;
    }

#pragma unroll 1
    for (int q = 0; q < 8; ++q) {
        float4 res0[4], res1[4];   // distinct regs per row (u unrolled)

        // ---- compute phase: 4 rows, no stores ----
#pragma unroll
        for (int u = 0; u < 4; ++u) {
            float4 a0 = ebs0, a1 = ebs1;
#pragma unroll
            for (int i = 0; i < Fc; ++i) {
                const float xi = rdlane(xq[0], u * 16 + i);   // compile-time lane
                a0.x = fmaf(xi, lo_f(p00[i]), a0.x);
                a0.y = fmaf(xi, hi_f(p00[i]), a0.y);
                a0.z = fmaf(xi, lo_f(p01[i]), a0.z);
                a0.w = fmaf(xi, hi_f(p01[i]), a0.w);
                a1.x = fmaf(xi, lo_f(p10[i]), a1.x);
                a1.y = fmaf(xi, hi_f(p10[i]), a1.y);
                a1.z = fmaf(xi, lo_f(p11[i]), a1.z);
                a1.w = fmaf(xi, hi_f(p11[i]), a1.w);
            }

            float psum = a0.x + a0.y + a0.z + a0.w + a1.x + a1.y + a1.z + a1.w;
            float pssq = fmaf(a0.x, a0.x, fmaf(a0.y, a0.y, fmaf(a0.z, a0.z, a0.w * a0.w)));
            pssq = fmaf(a1.x, a1.x, fmaf(a1.y, a1.y, fmaf(a1.z, a1.z, fmaf(a1.w, a1.w, pssq))));

            const float sum = wave_sum64(psum);
            const float ssq = wave_sum64(pssq);

            const float mean = sum * (1.0f / 512.0f);
            const float var  = ssq * (1.0f / 512.0f) - mean * mean;
            const float rs   = rsqrtf(var + LN_EPS);
            const float nmrs = -mean * rs;

            res0[u].x = fmaf(fmaf(a0.x, rs, nmrs), g0.x, be0.x);
            res0[u].y = fmaf(fmaf(a0.y, rs, nmrs), g0.y, be0.y);
            res0[u].z = fmaf(fmaf(a0.z, rs, nmrs), g0.z, be0.z);
            res0[u].w = fmaf(fmaf(a0.w, rs, nmrs), g0.w, be0.w);
            res1[u].x = fmaf(fmaf(a1.x, rs, nmrs), g1.x, be1.x);
            res1[u].y = fmaf(fmaf(a1.y, rs, nmrs), g1.y, be1.y);
            res1[u].z = fmaf(fmaf(a1.z, rs, nmrs), g1.z, be1.z);
            res1[u].w = fmaf(fmaf(a1.w, rs, nmrs), g1.w, be1.w);
        }

        // ---- burst phase: 8 stores back-to-back ----
#pragma unroll
        for (int u = 0; u < 4; ++u) {
            float* orow = out + ((size_t)(q * 4 + u) * NW + w) * Hc;
            *reinterpret_cast<float4*>(&orow[h0]) = res0[u];
            *reinterpret_cast<float4*>(&orow[h1]) = res1[u];
        }

        // shift-register rotation: next q consumes xq[0]
#pragma unroll
        for (int j = 0; j < 7; ++j) xq[j] = xq[j + 1];
    }
}

extern "C" void kernel_launch(void* const* d_in, const int* in_sizes, int n_in,
                              void* d_out, int out_size, void* d_ws, size_t ws_size,
                              hipStream_t stream) {
    const float* x     = (const float*)d_in[0];
    const float* W     = (const float*)d_in[1];
    const float* b     = (const float*)d_in[2];
    const float* emb   = (const float*)d_in[3];
    const float* gamma = (const float*)d_in[4];
    const float* beta  = (const float*)d_in[5];
    float* out  = (float*)d_out;
    float* bsum = (float*)d_ws;     // 512 floats

    bsum_kernel<<<Hc / 64, 64, 0, stream>>>(b, bsum);

    const int blocks = NW / 4;   // 1024 blocks x 4 waves
    fused_kernel<<<blocks, 256, 0, stream>>>(x, W, emb, bsum, gamma, beta, out);
}